// Round 1
// baseline (1138.847 us; speedup 1.0000x reference)
//
#include <hip/hip_runtime.h>
#include <math.h>

// ---------------- problem constants ----------------
#define NPTS 100000
#define KNB  16
#define NK   1600000            // NPTS*KNB

// output layout (float offsets)
#define OUT_XK   6400000        // after x_out [N,64]
#define OUT_KNN  108800000      // after xk [N,16,64]
#define OUT_PR   110400000      // after knn [N,16]

// workspace layout (float offsets)
#define WS_BNP_RAW 0            // 6   (sum3, ssq3)
#define WS_BN1_RAW 6            // 128 (sum64, ssq64)
#define WS_BN2_RAW 134          // 16  (sum8, ssq8)
#define WS_BNP_SS  160          // 6   (scale3, shift3)
#define WS_WS2     166          // 48  (16x3 shrunk lp_w2)
#define WS_WSB     214          // 16  (shrunk lp_b2)
#define WS_BN1_SS  230          // 128 (scale64, shift64)
#define WS_BN2_SS  358          // 16  (scale8, shift8)
#define WS_E       512          // NK*16
#define WS_PE      25600512     // NK*3
#define WS_T2      30400512     // NK*8
#define WS_XROW    43200512     // NPTS*64
// total = 49,600,512 floats = ~198.4 MB

#define GRID_NK 3125            // 3125 blocks * 256 thr * 2 iters = 1,600,000
#define NK_STRIDE 800000

// ---------------- kernels ----------------

__global__ __launch_bounds__(256) void k_xrow(
    const float* __restrict__ x, const float* __restrict__ w3,
    const float* __restrict__ b3, float* __restrict__ xrow)
{
    int n = blockIdx.x * 256 + threadIdx.x;
    if (n >= NPTS) return;
    float xr[64];
    const float4* xp = (const float4*)(x + (size_t)n * 64);
    #pragma unroll
    for (int i = 0; i < 16; ++i) {
        float4 v = xp[i];
        xr[4*i] = v.x; xr[4*i+1] = v.y; xr[4*i+2] = v.z; xr[4*i+3] = v.w;
    }
    for (int c = 0; c < 64; ++c) {          // c uniform -> w3 row via s_load
        const float* wr = w3 + c * 64;
        float acc = b3[c];
        #pragma unroll
        for (int q = 0; q < 64; ++q) acc += wr[q] * xr[q];
        xrow[(size_t)n * 64 + c] = acc;
    }
}

__global__ __launch_bounds__(256) void k_stage0(
    const float* __restrict__ p, const float* __restrict__ x, const int* __restrict__ knn,
    const float* __restrict__ w1, const float* __restrict__ b1,
    const float* __restrict__ bw, const float* __restrict__ bb,
    const float* __restrict__ lpw1, const float* __restrict__ lpb1,
    float* __restrict__ ws, float* __restrict__ out)
{
    float ps0=0.f, ps1=0.f, ps2=0.f, pq0=0.f, pq1=0.f, pq2=0.f;
    float* e_out  = ws + WS_E;
    float* pe_out = ws + WS_PE;
    float* o_knn  = out + OUT_KNN;
    float* o_pr   = out + OUT_PR;
    int id = blockIdx.x * 256 + threadIdx.x;
    for (int it = 0; it < 2; ++it, id += NK_STRIDE) {
        int n = id >> 4;
        int idx = knn[id];
        float pr0 = p[idx*3+0] - p[n*3+0];
        float pr1 = p[idx*3+1] - p[n*3+1];
        float pr2 = p[idx*3+2] - p[n*3+2];
        o_pr[id*3+0] = pr0; o_pr[id*3+1] = pr1; o_pr[id*3+2] = pr2;
        o_knn[id] = (float)idx;
        // pe = p_r @ lp_w1.T + lp_b1 ; accumulate BN-p stats
        {
            float v0 = lpb1[0] + lpw1[0]*pr0 + lpw1[1]*pr1 + lpw1[2]*pr2;
            float v1 = lpb1[1] + lpw1[3]*pr0 + lpw1[4]*pr1 + lpw1[5]*pr2;
            float v2 = lpb1[2] + lpw1[6]*pr0 + lpw1[7]*pr1 + lpw1[8]*pr2;
            pe_out[id*3+0] = v0; pe_out[id*3+1] = v1; pe_out[id*3+2] = v2;
            ps0 += v0; ps1 += v1; ps2 += v2;
            pq0 += v0*v0; pq1 += v1*v1; pq2 += v2*v2;
        }
        // gather x row
        float xr[64];
        const float4* xp = (const float4*)(x + (size_t)idx * 64);
        #pragma unroll
        for (int i = 0; i < 16; ++i) {
            float4 v = xp[i];
            xr[4*i] = v.x; xr[4*i+1] = v.y; xr[4*i+2] = v.z; xr[4*i+3] = v.w;
        }
        // e1 = relu([p_r, x] @ w1.T + b1)
        float e1[16];
        for (int j = 0; j < 16; ++j) {      // j uniform -> w1 row via s_load
            const float* wr = w1 + j * 67;
            float s = b1[j] + wr[0]*pr0 + wr[1]*pr1 + wr[2]*pr2;
            #pragma unroll
            for (int c = 0; c < 64; ++c) s += wr[3+c] * xr[c];
            e1[j] = fmaxf(s, 0.f);
        }
        // bilinear: e_out[o] = e1 . bw[o] . e1 + bb[o]
        for (int o = 0; o < 16; ++o) {      // uniform
            float acc = bb[o];
            const float* bo = bw + o * 256;
            for (int i = 0; i < 16; ++i) {  // uniform
                const float* br = bo + i * 16;
                float t = 0.f;
                #pragma unroll
                for (int j = 0; j < 16; ++j) t += br[j] * e1[j];
                acc += e1[i] * t;
            }
            e_out[id*16+o] = acc;
        }
    }
    // block-reduce BN-p stats -> global atomics
    #pragma unroll
    for (int off = 32; off; off >>= 1) {
        ps0 += __shfl_xor(ps0, off); ps1 += __shfl_xor(ps1, off); ps2 += __shfl_xor(ps2, off);
        pq0 += __shfl_xor(pq0, off); pq1 += __shfl_xor(pq1, off); pq2 += __shfl_xor(pq2, off);
    }
    __shared__ float sb[6];
    if (threadIdx.x < 6) sb[threadIdx.x] = 0.f;
    __syncthreads();
    if ((threadIdx.x & 63) == 0) {
        atomicAdd(&sb[0], ps0); atomicAdd(&sb[1], ps1); atomicAdd(&sb[2], ps2);
        atomicAdd(&sb[3], pq0); atomicAdd(&sb[4], pq1); atomicAdd(&sb[5], pq2);
    }
    __syncthreads();
    if (threadIdx.x < 6) atomicAdd(&ws[WS_BNP_RAW + threadIdx.x], sb[threadIdx.x]);
}

__global__ void k_fin_bnp(float* __restrict__ ws,
    const float* __restrict__ g, const float* __restrict__ b,
    const float* __restrict__ lpw2, const float* __restrict__ lpb2)
{
    int t = threadIdx.x;
    if (t < 3) {
        float mean = ws[WS_BNP_RAW + t] / (float)NK;
        float var  = ws[WS_BNP_RAW + 3 + t] / (float)NK - mean * mean;
        float sc = g[t] * rsqrtf(var + 1e-5f);
        ws[WS_BNP_SS + t] = sc;
        ws[WS_BNP_SS + 3 + t] = b[t] - mean * sc;
    }
    if (t >= 16 && t < 64) {   // shrunk lp_w2: ws2[j][d] = sum_a lp_w2[a*16+j][d]
        int r = t - 16, j = r / 3, d = r % 3;
        ws[WS_WS2 + r] = lpw2[(j)*3+d] + lpw2[(16+j)*3+d] + lpw2[(32+j)*3+d] + lpw2[(48+j)*3+d];
    }
    if (t >= 64 && t < 80) {
        int j = t - 64;
        ws[WS_WSB + j] = lpb2[j] + lpb2[16+j] + lpb2[32+j] + lpb2[48+j];
    }
}

__device__ __forceinline__ void build_energy(
    const float* __restrict__ e_in, const float* __restrict__ pe_in,
    const float* __restrict__ wsro, int id, float* en)
{
    const float4* ep = (const float4*)(e_in + id * 16);
    #pragma unroll
    for (int i = 0; i < 4; ++i) {
        float4 v = ep[i];
        en[4*i] = v.x; en[4*i+1] = v.y; en[4*i+2] = v.z; en[4*i+3] = v.w;
    }
    float q0 = fmaxf(pe_in[id*3+0]*wsro[WS_BNP_SS+0] + wsro[WS_BNP_SS+3], 0.f);
    float q1 = fmaxf(pe_in[id*3+1]*wsro[WS_BNP_SS+1] + wsro[WS_BNP_SS+4], 0.f);
    float q2 = fmaxf(pe_in[id*3+2]*wsro[WS_BNP_SS+2] + wsro[WS_BNP_SS+5], 0.f);
    #pragma unroll
    for (int j = 0; j < 16; ++j) {
        en[16+j] = wsro[WS_WSB+j] + wsro[WS_WS2+j*3]*q0 + wsro[WS_WS2+j*3+1]*q1 + wsro[WS_WS2+j*3+2]*q2;
    }
}

__global__ __launch_bounds__(256) void k_stats1(
    const float* __restrict__ wsro, const float* __restrict__ c1w, float* __restrict__ ws)
{
    __shared__ float sacc[128];
    if (threadIdx.x < 128) sacc[threadIdx.x] = 0.f;
    __syncthreads();
    const float* e_in  = wsro + WS_E;
    const float* pe_in = wsro + WS_PE;
    int id = blockIdx.x * 256 + threadIdx.x;
    for (int it = 0; it < 2; ++it, id += NK_STRIDE) {
        float en[32];
        build_energy(e_in, pe_in, wsro, id, en);
        for (int c = 0; c < 64; ++c) {       // uniform -> s_load weights
            const float* wr = c1w + c * 32;
            float t = 0.f;
            #pragma unroll
            for (int q = 0; q < 32; ++q) t += wr[q] * en[q];
            float s = t, s2 = t * t;
            #pragma unroll
            for (int off = 32; off; off >>= 1) { s += __shfl_xor(s, off); s2 += __shfl_xor(s2, off); }
            if ((threadIdx.x & 63) == 0) { atomicAdd(&sacc[c], s); atomicAdd(&sacc[64+c], s2); }
        }
    }
    __syncthreads();
    if (threadIdx.x < 128) atomicAdd(&ws[WS_BN1_RAW + threadIdx.x], sacc[threadIdx.x]);
}

__global__ void k_fin_bn1(float* __restrict__ ws, const float* __restrict__ g, const float* __restrict__ b)
{
    int c = threadIdx.x;
    if (c < 64) {
        float mean = ws[WS_BN1_RAW + c] / (float)NK;
        float var  = ws[WS_BN1_RAW + 64 + c] / (float)NK - mean * mean;
        float sc = g[c] * rsqrtf(var + 1e-5f);
        ws[WS_BN1_SS + c] = sc;
        ws[WS_BN1_SS + 64 + c] = b[c] - mean * sc;
    }
}

__global__ __launch_bounds__(256) void k_stage2(
    const float* __restrict__ wsro, const float* __restrict__ c1w,
    const float* __restrict__ c2w, float* __restrict__ ws)
{
    float tsum[8] = {0,0,0,0,0,0,0,0}, tssq[8] = {0,0,0,0,0,0,0,0};
    const float* e_in  = wsro + WS_E;
    const float* pe_in = wsro + WS_PE;
    float* t2 = ws + WS_T2;
    int id = blockIdx.x * 256 + threadIdx.x;
    for (int it = 0; it < 2; ++it, id += NK_STRIDE) {
        float en[32];
        build_energy(e_in, pe_in, wsro, id, en);
        float t2a[8] = {0,0,0,0,0,0,0,0};
        for (int c = 0; c < 64; ++c) {       // uniform
            const float* wr = c1w + c * 32;
            float t = 0.f;
            #pragma unroll
            for (int q = 0; q < 32; ++q) t += wr[q] * en[q];
            float h = fmaxf(t * wsro[WS_BN1_SS + c] + wsro[WS_BN1_SS + 64 + c], 0.f);
            #pragma unroll
            for (int c2 = 0; c2 < 8; ++c2) t2a[c2] += h * c2w[c2 * 64 + c];
        }
        float4* t2p = (float4*)(t2 + id * 8);
        t2p[0] = make_float4(t2a[0], t2a[1], t2a[2], t2a[3]);
        t2p[1] = make_float4(t2a[4], t2a[5], t2a[6], t2a[7]);
        #pragma unroll
        for (int c2 = 0; c2 < 8; ++c2) { tsum[c2] += t2a[c2]; tssq[c2] += t2a[c2] * t2a[c2]; }
    }
    __shared__ float sacc[16];
    if (threadIdx.x < 16) sacc[threadIdx.x] = 0.f;
    __syncthreads();
    #pragma unroll
    for (int c2 = 0; c2 < 8; ++c2) {
        float s = tsum[c2], s2 = tssq[c2];
        #pragma unroll
        for (int off = 32; off; off >>= 1) { s += __shfl_xor(s, off); s2 += __shfl_xor(s2, off); }
        if ((threadIdx.x & 63) == 0) { atomicAdd(&sacc[c2], s); atomicAdd(&sacc[8 + c2], s2); }
    }
    __syncthreads();
    if (threadIdx.x < 16) atomicAdd(&ws[WS_BN2_RAW + threadIdx.x], sacc[threadIdx.x]);
}

__global__ void k_fin_bn2(float* __restrict__ ws, const float* __restrict__ g, const float* __restrict__ b)
{
    int c = threadIdx.x;
    if (c < 8) {
        float mean = ws[WS_BN2_RAW + c] / (float)NK;
        float var  = ws[WS_BN2_RAW + 8 + c] / (float)NK - mean * mean;
        float sc = g[c] * rsqrtf(var + 1e-5f);
        ws[WS_BN2_SS + c] = sc;
        ws[WS_BN2_SS + 8 + c] = b[c] - mean * sc;
    }
}

__global__ __launch_bounds__(128) void k_final(
    const int* __restrict__ knn, const float* __restrict__ wsro,
    const float* __restrict__ c3w, const float* __restrict__ c3b,
    const float* __restrict__ lpw2, const float* __restrict__ lpb2,
    float* __restrict__ out)
{
    int n = blockIdx.x, t = threadIdx.x;
    __shared__ float h2s[16][8], ssm[16][8], wls[16][8], pes[16][3], red[128];
    __shared__ int idxs[16];
    const float* t2   = wsro + WS_T2;
    const float* pe   = wsro + WS_PE;
    const float* xrow = wsro + WS_XROW;
    if (t < 16) idxs[t] = knn[n * 16 + t];
    {
        int k = t >> 3, c2 = t & 7;
        float v = t2[n * 128 + t];
        h2s[k][c2] = fmaxf(v * wsro[WS_BN2_SS + c2] + wsro[WS_BN2_SS + 8 + c2], 0.f);
    }
    if (t < 48) {
        int k = t / 3, d = t % 3;
        pes[k][d] = fmaxf(pe[n * 48 + t] * wsro[WS_BNP_SS + d] + wsro[WS_BNP_SS + 3 + d], 0.f);
    }
    __syncthreads();
    {
        int k = t >> 3, cc = t & 7;
        float s = c3b[cc];
        #pragma unroll
        for (int q = 0; q < 8; ++q) s += h2s[k][q] * c3w[cc * 8 + q];
        ssm[k][cc] = s;
    }
    __syncthreads();
    if (t < 8) {   // softmax over k for channel t
        float m = -1e30f;
        for (int k = 0; k < 16; ++k) m = fmaxf(m, ssm[k][t]);
        float sum = 0.f;
        for (int k = 0; k < 16; ++k) { float ev = __expf(ssm[k][t] - m); wls[k][t] = ev; sum += ev; }
        float inv = 1.f / sum;
        for (int k = 0; k < 16; ++k) wls[k][t] *= inv;
    }
    __syncthreads();
    int c = t & 63, kh = t >> 6;
    float w20 = lpw2[c*3], w21 = lpw2[c*3+1], w22 = lpw2[c*3+2], bc = lpb2[c];
    float acc = 0.f;
    float* out_xk = out + OUT_XK + (size_t)n * 1024;
    #pragma unroll
    for (int i = 0; i < 8; ++i) {
        int k = kh * 8 + i;
        float xv = xrow[(size_t)idxs[k] * 64 + c];
        float pemb = bc + w20 * pes[k][0] + w21 * pes[k][1] + w22 * pes[k][2];
        float val = (xv + pemb) * wls[k][c & 7];
        out_xk[k * 64 + c] = val;
        acc += val;
    }
    red[t] = acc;
    __syncthreads();
    if (t < 64) out[(size_t)n * 64 + t] = red[t] + red[t + 64];
}

// ---------------- launch ----------------
extern "C" void kernel_launch(void* const* d_in, const int* in_sizes, int n_in,
                              void* d_out, int out_size, void* d_ws, size_t ws_size,
                              hipStream_t stream)
{
    (void)in_sizes; (void)n_in; (void)out_size; (void)ws_size;
    const float* p    = (const float*)d_in[0];
    const float* x    = (const float*)d_in[1];
    const int*   knn  = (const int*)  d_in[2];
    const float* w1   = (const float*)d_in[3];
    const float* b1   = (const float*)d_in[4];
    const float* bw   = (const float*)d_in[5];
    const float* bb   = (const float*)d_in[6];
    const float* lpw1 = (const float*)d_in[7];
    const float* lpb1 = (const float*)d_in[8];
    const float* bnpg = (const float*)d_in[9];
    const float* bnpb = (const float*)d_in[10];
    const float* lpw2 = (const float*)d_in[11];
    const float* lpb2 = (const float*)d_in[12];
    const float* c1w  = (const float*)d_in[13];
    const float* bn1g = (const float*)d_in[14];
    const float* bn1b = (const float*)d_in[15];
    const float* c2w  = (const float*)d_in[16];
    const float* bn2g = (const float*)d_in[17];
    const float* bn2b = (const float*)d_in[18];
    const float* c3w  = (const float*)d_in[19];
    const float* c3b  = (const float*)d_in[20];
    const float* w3   = (const float*)d_in[21];
    const float* b3   = (const float*)d_in[22];
    float* out = (float*)d_out;
    float* ws  = (float*)d_ws;

    hipMemsetAsync(ws, 0, 160 * sizeof(float), stream);
    k_xrow  <<<(NPTS + 255) / 256, 256, 0, stream>>>(x, w3, b3, ws + WS_XROW);
    k_stage0<<<GRID_NK, 256, 0, stream>>>(p, x, knn, w1, b1, bw, bb, lpw1, lpb1, ws, out);
    k_fin_bnp<<<1, 128, 0, stream>>>(ws, bnpg, bnpb, lpw2, lpb2);
    k_stats1<<<GRID_NK, 256, 0, stream>>>(ws, c1w, ws);
    k_fin_bn1<<<1, 64, 0, stream>>>(ws, bn1g, bn1b);
    k_stage2<<<GRID_NK, 256, 0, stream>>>(ws, c1w, c2w, ws);
    k_fin_bn2<<<1, 64, 0, stream>>>(ws, bn2g, bn2b);
    k_final <<<NPTS, 128, 0, stream>>>(knn, ws, c3w, c3b, lpw2, lpb2, out);
}